// Round 2
// baseline (733.227 us; speedup 1.0000x reference)
//
#include <hip/hip_runtime.h>
#include <stdint.h>

#define B_ 32
#define N_ 2048
#define D_ 1024
#define H_ 16

typedef __attribute__((ext_vector_type(8))) short short8;
typedef __attribute__((ext_vector_type(4))) float f32x4;

__device__ __forceinline__ unsigned short f2bf(float x) {
    unsigned u = __float_as_uint(x);
    u += 0x7FFFu + ((u >> 16) & 1u);   // RNE
    return (unsigned short)(u >> 16);
}
__device__ __forceinline__ float bfhi(unsigned u) { return __uint_as_float(u & 0xFFFF0000u); }
__device__ __forceinline__ float bflo(unsigned u) { return __uint_as_float(u << 16); }

// ---------------------------------------------------------------------------
// prep_k: blocks 0..15 (h): q[64h+j] = query . w_q[64h+j,:] + b_q, then
//   R[h,d] = 0.125 * sum_j q[64h+j] w_k[64h+j,d] packed as bf16 MFMA A-frags.
// blocks 16..47: any_ws[b] = OR over mask row b.
// ---------------------------------------------------------------------------
__global__ __launch_bounds__(256) void prep_k(const float* __restrict__ query,
        const float* __restrict__ w_q, const float* __restrict__ b_q,
        const float* __restrict__ w_k, const int* __restrict__ mask,
        unsigned short* __restrict__ rAf, int* __restrict__ any_ws) {
    __shared__ __align__(16) float qv[1024];
    __shared__ float qpart[64][4];
    __shared__ float qh[64];
    __shared__ int wf[4];
    int bx = blockIdx.x, t = threadIdx.x;
    if (bx < 16) {
        int h = bx;
        *(float4*)&qv[4 * t] = *(const float4*)&query[4 * t];
        __syncthreads();
        // ---- phase 0: q row for this head (64 outputs, 4 threads each) ----
        {
            int j = t >> 2, qr = t & 3;
            const float4* wq4 = (const float4*)w_q;
            const float4* qv4 = (const float4*)qv;
            float a = 0.f;
            #pragma unroll 4
            for (int kk = 0; kk < 64; kk++) {
                float4 wv = wq4[(size_t)(h * 64 + j) * 256 + qr * 64 + kk];
                float4 vv = qv4[qr * 64 + kk];
                a += wv.x * vv.x + wv.y * vv.y + wv.z * vv.z + wv.w * vv.w;
            }
            qpart[j][qr] = a;
        }
        __syncthreads();
        if (t < 64)
            qh[t] = qpart[t][0] + qpart[t][1] + qpart[t][2] + qpart[t][3] + b_q[h * 64 + t];
        __syncthreads();
        // ---- phase 1: R = (q_h^T @ w_k slice) * 1/8, pack A-fragments ----
        float4 acc = make_float4(0.f, 0.f, 0.f, 0.f);
        const float4* wk4 = (const float4*)w_k;
        #pragma unroll 4
        for (int jj = 0; jj < 64; jj++) {
            float qq = qh[jj];
            float4 wv = wk4[(size_t)(h * 64 + jj) * 256 + t];
            acc.x += qq * wv.x; acc.y += qq * wv.y;
            acc.z += qq * wv.z; acc.w += qq * wv.w;
        }
        const float scale = 0.125f;    // 1/sqrt(64) folded into R
        float av[4] = {acc.x * scale, acc.y * scale, acc.z * scale, acc.w * scale};
        #pragma unroll
        for (int dd = 0; dd < 4; dd++) {
            int d = 4 * t + dd;
            int i = d >> 5, g = (d >> 3) & 3, jj = d & 7;
            int lane = (g << 4) | h;   // A[m=lane&15][k=(lane>>4)*8+j]
            rAf[(size_t)(i * 64 + lane) * 8 + jj] = f2bf(av[dd]);
        }
    } else {
        int b = bx - 16;
        int v = 0;
        for (int k = 0; k < 8; k++) v |= mask[b * N_ + k * 256 + t];
        unsigned long long bal = __ballot(v != 0);
        int w = t >> 6;
        if ((t & 63) == 0) wf[w] = (bal != 0ull) ? 1 : 0;
        __syncthreads();
        if (t == 0) any_ws[b] = wf[0] | wf[1] | wf[2] | wf[3];
    }
}

// ---------------------------------------------------------------------------
// main_k: grid 512 (b = bx>>4, chunk c = bx&15 -> 128 rows, 8 x 16-row tiles).
// Double-buffered bf16 z tile in LDS (+16 ushort row pad: conflict-free
// score-phase ds_read_b128). Scores via mfma_f32_16x16x32_bf16, ctx via
// register outer-product accumulation. Writes f32 partial ctx + l.
// ---------------------------------------------------------------------------
__global__ __launch_bounds__(256, 2) void main_k(const float* __restrict__ z,
        const int* __restrict__ mask, const int* __restrict__ any_ws,
        const unsigned short* __restrict__ rAf,
        float* __restrict__ part, float* __restrict__ l_part) {
    __shared__ __align__(16) unsigned short zt[2][16][1040];  // 65 KB (padded)
    __shared__ float Cpart[4][16][16];
    __shared__ float E_lds[256];
    __shared__ float lred[256];
    int bx = blockIdx.x, t = threadIdx.x;
    int b = bx >> 4, c = bx & 15;
    int n0 = c * 128;
    int w = t >> 6, l = t & 63;
    int frow = l & 15, fquad = l >> 4;        // MFMA fragment coords
    int eh = t & 15, en = t >> 4;             // (h, n) for E phase
    int anyb = any_ws[b];
    const float4* zg4 = (const float4*)(z + (size_t)b * N_ * D_);
    const short8* rA8 = (const short8*)rAf;
    float4 ctx[16];
    #pragma unroll
    for (int h = 0; h < 16; h++) ctx[h] = make_float4(0.f, 0.f, 0.f, 0.f);
    float l_acc = 0.f;

    // preload tile 0 into buffer 0
    float4 vv[16];
    #pragma unroll
    for (int k = 0; k < 16; k++) vv[k] = zg4[(size_t)(n0 + k) * 256 + t];
    #pragma unroll
    for (int k = 0; k < 16; k++) {
        ushort4 o;
        o.x = f2bf(vv[k].x); o.y = f2bf(vv[k].y);
        o.z = f2bf(vv[k].z); o.w = f2bf(vv[k].w);
        *(ushort4*)&zt[0][k][4 * t] = o;
    }

    for (int it = 0; it < 8; it++) {
        int p = it & 1;
        __syncthreads();                      // publish zt[p]
        // --- prefetch next tile (overlaps with the whole compute phase) ---
        if (it < 7) {
            int rb = n0 + (it + 1) * 16;
            #pragma unroll
            for (int k = 0; k < 16; k++) vv[k] = zg4[(size_t)(rb + k) * 256 + t];
        }
        // --- scores: wave w covers d in [256w, 256w+256), 8 MFMAs ---
        f32x4 acc = {0.f, 0.f, 0.f, 0.f};
        #pragma unroll
        for (int ib = 0; ib < 8; ib++) {
            int i = w * 8 + ib;
            short8 af = rA8[i * 64 + l];
            short8 bf = *(const short8*)&zt[p][frow][i * 32 + fquad * 8];
            acc = __builtin_amdgcn_mfma_f32_16x16x32_bf16(af, bf, acc, 0, 0, 0);
        }
        #pragma unroll
        for (int r = 0; r < 4; r++) Cpart[w][fquad * 4 + r][frow] = acc[r];
        __syncthreads();
        // --- E = masked exp(s); scores are O(0.1) so no max-subtraction ---
        {
            int gn = n0 + it * 16 + en;
            float s = Cpart[0][eh][en] + Cpart[1][eh][en]
                    + Cpart[2][eh][en] + Cpart[3][eh][en];
            bool valid = (mask[b * N_ + gn] != 0) || (gn == 0 && anyb == 0);
            float e = valid ? __expf(s) : 0.f;
            E_lds[t] = e;                     // layout e[n][h]
            l_acc += e;
        }
        __syncthreads();
        // --- ctx accumulation: thread owns d = [4t,4t+4), all 16 heads ---
        for (int r = 0; r < 16; r++) {
            float er[16];
            *(float4*)&er[0]  = *(const float4*)&E_lds[r * 16 + 0];
            *(float4*)&er[4]  = *(const float4*)&E_lds[r * 16 + 4];
            *(float4*)&er[8]  = *(const float4*)&E_lds[r * 16 + 8];
            *(float4*)&er[12] = *(const float4*)&E_lds[r * 16 + 12];
            uint2 pz = *(const uint2*)&zt[p][r][4 * t];
            float z0 = bflo(pz.x), z1 = bfhi(pz.x), z2 = bflo(pz.y), z3 = bfhi(pz.y);
            #pragma unroll
            for (int h = 0; h < 16; h++) {
                float e = er[h];
                ctx[h].x += e * z0; ctx[h].y += e * z1;
                ctx[h].z += e * z2; ctx[h].w += e * z3;
            }
        }
        // --- convert + store next tile into the other buffer ---
        if (it < 7) {
            #pragma unroll
            for (int k = 0; k < 16; k++) {
                ushort4 o;
                o.x = f2bf(vv[k].x); o.y = f2bf(vv[k].y);
                o.z = f2bf(vv[k].z); o.w = f2bf(vv[k].w);
                *(ushort4*)&zt[p ^ 1][k][4 * t] = o;
            }
        }
    }
    // --- write f32 per-chunk partials ---
    #pragma unroll
    for (int h = 0; h < 16; h++)
        *(float4*)&part[((size_t)bx * 16 + h) * 1024 + 4 * t] = ctx[h];
    lred[t] = l_acc;
    __syncthreads();
    if (t < 16) {
        float s = 0.f;
        #pragma unroll
        for (int g = 0; g < 16; g++) s += lred[g * 16 + t];
        l_part[bx * 16 + t] = s;
    }
}

// ---------------------------------------------------------------------------
// gemv_wv_k: block (b, h). Phase A: vlds = (sum_c part[b][c][h][:]) / L[b][h].
// Phase B: pooled[b][64h+j] = w_v[64h+j,:] . vlds + b_v  (4-acc ILP GEMV).
// ---------------------------------------------------------------------------
__global__ __launch_bounds__(256) void gemv_wv_k(const float* __restrict__ part,
        const float* __restrict__ l_part, const float* __restrict__ w_v,
        const float* __restrict__ b_v, float* __restrict__ pooled) {
    __shared__ __align__(16) float vlds[1024];
    int bx = blockIdx.x, t = threadIdx.x;
    int b = bx >> 4, h = bx & 15;
    float L = 0.f;
    #pragma unroll
    for (int cc = 0; cc < 16; cc++) L += l_part[(b * 16 + cc) * 16 + h];
    float rL = 1.f / L;
    float sx = 0.f, sy = 0.f, sz = 0.f, sw = 0.f;
    #pragma unroll
    for (int cc = 0; cc < 16; cc++) {
        const float4* p4 = (const float4*)&part[(((size_t)(b * 16 + cc)) * 16 + h) * 1024];
        float4 v = p4[t];
        sx += v.x; sy += v.y; sz += v.z; sw += v.w;
    }
    float4 o = make_float4(sx * rL, sy * rL, sz * rL, sw * rL);
    *(float4*)&vlds[4 * t] = o;
    __syncthreads();
    int w = t >> 6, l = t & 63;
    const float4* v4 = (const float4*)vlds;
    float* orow = pooled + (size_t)b * 1024;
    #pragma unroll
    for (int s0 = 0; s0 < 16; s0 += 4) {
        int jb = h * 64 + w * 16 + s0;
        float a0 = 0.f, a1 = 0.f, a2 = 0.f, a3 = 0.f;
        #pragma unroll
        for (int kk = 0; kk < 4; kk++) {
            float4 v = v4[kk * 64 + l];
            float4 w0 = *(const float4*)&w_v[(size_t)(jb + 0) * 1024 + (kk * 64 + l) * 4];
            float4 w1 = *(const float4*)&w_v[(size_t)(jb + 1) * 1024 + (kk * 64 + l) * 4];
            float4 w2 = *(const float4*)&w_v[(size_t)(jb + 2) * 1024 + (kk * 64 + l) * 4];
            float4 w3 = *(const float4*)&w_v[(size_t)(jb + 3) * 1024 + (kk * 64 + l) * 4];
            a0 += w0.x * v.x + w0.y * v.y + w0.z * v.z + w0.w * v.w;
            a1 += w1.x * v.x + w1.y * v.y + w1.z * v.z + w1.w * v.w;
            a2 += w2.x * v.x + w2.y * v.y + w2.z * v.z + w2.w * v.w;
            a3 += w3.x * v.x + w3.y * v.y + w3.z * v.z + w3.w * v.w;
        }
        #pragma unroll
        for (int m = 32; m >= 1; m >>= 1) {
            a0 += __shfl_xor(a0, m, 64); a1 += __shfl_xor(a1, m, 64);
            a2 += __shfl_xor(a2, m, 64); a3 += __shfl_xor(a3, m, 64);
        }
        if (l == 0) {
            orow[jb + 0] = a0 + b_v[jb + 0];
            orow[jb + 1] = a1 + b_v[jb + 1];
            orow[jb + 2] = a2 + b_v[jb + 2];
            orow[jb + 3] = a3 + b_v[jb + 3];
        }
    }
}

// ---------------------------------------------------------------------------
// gemv_wo_k: block (b, q). out[b][64q+j] = w_o[64q+j,:] . pooled[b] + b_o
// ---------------------------------------------------------------------------
__global__ __launch_bounds__(256) void gemv_wo_k(const float* __restrict__ pooled,
        const float* __restrict__ w_o, const float* __restrict__ b_o,
        float* __restrict__ out) {
    __shared__ __align__(16) float vlds[1024];
    int bx = blockIdx.x, t = threadIdx.x;
    int b = bx >> 4, q = bx & 15;
    *(float4*)&vlds[4 * t] = *(const float4*)&pooled[(size_t)b * 1024 + 4 * t];
    __syncthreads();
    int w = t >> 6, l = t & 63;
    const float4* v4 = (const float4*)vlds;
    float* orow = out + (size_t)b * 1024;
    #pragma unroll
    for (int s0 = 0; s0 < 16; s0 += 4) {
        int jb = q * 64 + w * 16 + s0;
        float a0 = 0.f, a1 = 0.f, a2 = 0.f, a3 = 0.f;
        #pragma unroll
        for (int kk = 0; kk < 4; kk++) {
            float4 v = v4[kk * 64 + l];
            float4 w0 = *(const float4*)&w_o[(size_t)(jb + 0) * 1024 + (kk * 64 + l) * 4];
            float4 w1 = *(const float4*)&w_o[(size_t)(jb + 1) * 1024 + (kk * 64 + l) * 4];
            float4 w2 = *(const float4*)&w_o[(size_t)(jb + 2) * 1024 + (kk * 64 + l) * 4];
            float4 w3 = *(const float4*)&w_o[(size_t)(jb + 3) * 1024 + (kk * 64 + l) * 4];
            a0 += w0.x * v.x + w0.y * v.y + w0.z * v.z + w0.w * v.w;
            a1 += w1.x * v.x + w1.y * v.y + w1.z * v.z + w1.w * v.w;
            a2 += w2.x * v.x + w2.y * v.y + w2.z * v.z + w2.w * v.w;
            a3 += w3.x * v.x + w3.y * v.y + w3.z * v.z + w3.w * v.w;
        }
        #pragma unroll
        for (int m = 32; m >= 1; m >>= 1) {
            a0 += __shfl_xor(a0, m, 64); a1 += __shfl_xor(a1, m, 64);
            a2 += __shfl_xor(a2, m, 64); a3 += __shfl_xor(a3, m, 64);
        }
        if (l == 0) {
            orow[jb + 0] = a0 + b_o[jb + 0];
            orow[jb + 1] = a1 + b_o[jb + 1];
            orow[jb + 2] = a2 + b_o[jb + 2];
            orow[jb + 3] = a3 + b_o[jb + 3];
        }
    }
}

// ---------------------------------------------------------------------------
extern "C" void kernel_launch(void* const* d_in, const int* in_sizes, int n_in,
                              void* d_out, int out_size, void* d_ws, size_t ws_size,
                              hipStream_t stream) {
    const float* z     = (const float*)d_in[0];
    const int*   mask  = (const int*)d_in[1];
    const float* query = (const float*)d_in[2];
    const float* w_q   = (const float*)d_in[3];
    const float* w_k   = (const float*)d_in[4];
    const float* w_v   = (const float*)d_in[5];
    const float* b_q   = (const float*)d_in[6];
    // d_in[7] = b_k: constant per (b,h) over n -> cancels in softmax
    const float* b_v   = (const float*)d_in[8];
    const float* w_o   = (const float*)d_in[9];
    const float* b_o   = (const float*)d_in[10];
    float* out = (float*)d_out;

    char* ws = (char*)d_ws;
    unsigned short* rAf    = (unsigned short*)(ws + 0);       // 32 KB
    int*            any_ws = (int*)(ws + 32768);              // 128 B
    float*          l_part = (float*)(ws + 65536);            // 32 KB
    float*          pooled = (float*)(ws + 131072);           // 128 KB
    float*          part   = (float*)(ws + 1048576);          // 32 MB

    prep_k<<<48, 256, 0, stream>>>(query, w_q, b_q, w_k, mask, rAf, any_ws);
    main_k<<<512, 256, 0, stream>>>(z, mask, any_ws, rAf, part, l_part);
    gemv_wv_k<<<512, 256, 0, stream>>>(part, l_part, w_v, b_v, pooled);
    gemv_wo_k<<<512, 256, 0, stream>>>(pooled, w_o, b_o, out);
}

// Round 3
// 460.217 us; speedup vs baseline: 1.5932x; 1.5932x over previous
//
#include <hip/hip_runtime.h>
#include <hip/hip_bf16.h>
#include <stdint.h>

#define B_ 32
#define N_ 2048
#define D_ 1024
#define H_ 16

#define NT 16          // 16-row tiles per block (256 rows/block)
#define RPAD 1028      // f32 row stride in LDS (+4 pad: de-conflicts frow reads)

typedef __attribute__((ext_vector_type(8))) short short8;
typedef __attribute__((ext_vector_type(4))) float f32x4;

__device__ __forceinline__ unsigned short f2bf(float x) {
    unsigned u = __float_as_uint(x);
    u += 0x7FFFu + ((u >> 16) & 1u);   // RNE
    return (unsigned short)(u >> 16);
}

// pack 8 f32 -> short8 bf16 (RNE, packed cvt where available)
__device__ __forceinline__ short8 cvt8(float4 a, float4 b) {
    union { __hip_bfloat162 h[4]; short8 s; } u;
    u.h[0] = __float22bfloat162_rn(make_float2(a.x, a.y));
    u.h[1] = __float22bfloat162_rn(make_float2(a.z, a.w));
    u.h[2] = __float22bfloat162_rn(make_float2(b.x, b.y));
    u.h[3] = __float22bfloat162_rn(make_float2(b.z, b.w));
    return u.s;
}

// ---------------------------------------------------------------------------
// prep_q: blocks 0..63 (h=bx>>2, jg=bx&3): q[64h+16jg+jl] = query.w_q[row]+b_q
//         blocks 64..95: any_ws[b] = OR over mask row (b = bx-64)
// ---------------------------------------------------------------------------
__global__ __launch_bounds__(256) void prep_q(const float* __restrict__ query,
        const float* __restrict__ w_q, const float* __restrict__ b_q,
        const int* __restrict__ mask, float* __restrict__ q_ws,
        int* __restrict__ any_ws) {
    __shared__ __align__(16) float qv[1024];
    __shared__ float qp[16][17];
    __shared__ int wf[4];
    int bx = blockIdx.x, t = threadIdx.x;
    if (bx < 64) {
        int h = bx >> 2, jg = bx & 3;
        *(float4*)&qv[4 * t] = *(const float4*)&query[4 * t];
        __syncthreads();
        int jl = t >> 4, sub = t & 15;
        int j = h * 64 + jg * 16 + jl;
        const float4* wq4 = (const float4*)(w_q + (size_t)j * 1024);
        const float4* qv4 = (const float4*)qv;
        float a = 0.f;
        #pragma unroll
        for (int kk = 0; kk < 16; kk++) {
            float4 wv = wq4[sub * 16 + kk];
            float4 vv = qv4[sub * 16 + kk];
            a += wv.x * vv.x + wv.y * vv.y + wv.z * vv.z + wv.w * vv.w;
        }
        qp[jl][sub] = a;
        __syncthreads();
        if (sub == 0) {
            float s = 0.f;
            #pragma unroll
            for (int k2 = 0; k2 < 16; k2++) s += qp[jl][k2];
            q_ws[j] = s + b_q[j];
        }
    } else {
        int b = bx - 64;
        int v = 0;
        for (int k = 0; k < 8; k++) v |= mask[b * N_ + k * 256 + t];
        unsigned long long bal = __ballot(v != 0);
        int w = t >> 6;
        if ((t & 63) == 0) wf[w] = (bal != 0ull) ? 1 : 0;
        __syncthreads();
        if (t == 0) any_ws[b] = wf[0] | wf[1] | wf[2] | wf[3];
    }
}

// ---------------------------------------------------------------------------
// prep_r: 64 blocks (h=bx>>2, dg=bx&3). R[h][d] = 0.125 * sum_j q[64h+j]
//   * w_k[64h+j][d] for d in [256dg,+256), packed as bf16 MFMA A-fragments.
// ---------------------------------------------------------------------------
__global__ __launch_bounds__(256) void prep_r(const float* __restrict__ q_ws,
        const float* __restrict__ w_k, unsigned short* __restrict__ rAf) {
    __shared__ float qh[64];
    int bx = blockIdx.x, t = threadIdx.x;
    int h = bx >> 2, dg = bx & 3;
    if (t < 64) qh[t] = q_ws[h * 64 + t];
    __syncthreads();
    int d = dg * 256 + t;
    float acc = 0.f;
    #pragma unroll 4
    for (int j = 0; j < 64; j++)
        acc += qh[j] * w_k[(size_t)(h * 64 + j) * 1024 + d];
    acc *= 0.125f;                       // 1/sqrt(64) folded into R
    int i = d >> 5, fq = (d >> 3) & 3, jj = d & 7;
    int lane = (fq << 4) | h;            // A[m=lane&15][k=(lane>>4)*8+j]
    rAf[(size_t)(i * 64 + lane) * 8 + jj] = f2bf(acc);
}

// ---------------------------------------------------------------------------
// main_k: grid 256 (b=bx>>3, chunk c=bx&7 -> 256 rows, 16 x 16-row tiles).
// f32 z tile staged via global_load_lds (async, zero VGPR), double-buffered;
// ONE __syncthreads per tile — its vmcnt(0) drain IS the prefetch wait.
// Every wave computes full-d scores (32 MFMA, A-frags in 128 VGPRs) so no
// cross-wave reduction barrier; E tile is wave-private LDS.
// ---------------------------------------------------------------------------
__global__ __launch_bounds__(256, 1) void main_k(const float* __restrict__ z,
        const int* __restrict__ mask, const int* __restrict__ any_ws,
        const unsigned short* __restrict__ rAf,
        float* __restrict__ part, float* __restrict__ l_part) {
    __shared__ __align__(16) float zt[2][16 * RPAD];   // 131,584 B
    __shared__ __align__(16) float Ew[4][16][16];      // wave-private e[n][h]
    int bx = blockIdx.x, t = threadIdx.x;
    int b = bx >> 3, c = bx & 7;
    int n0 = c * 256;
    int w = t >> 6, l = t & 63;
    int frow = l & 15, fquad = l >> 4;
    int anyb = any_ws[b];

    // preload all 32 A-fragments (128 VGPRs, launch_bounds(256,1) -> no spill)
    short8 rA[32];
    {
        const short8* rA8 = (const short8*)rAf;
        #pragma unroll
        for (int i = 0; i < 32; i++) rA[i] = rA8[i * 64 + l];
    }
    const float* zb = z + (size_t)b * N_ * D_ + n0 * D_;

    float4 ctx[16];
    #pragma unroll
    for (int h = 0; h < 16; h++) ctx[h] = make_float4(0.f, 0.f, 0.f, 0.f);
    float l4[4] = {0.f, 0.f, 0.f, 0.f};

    // async stage one 16-row tile: wave w loads quarter w of each row.
    // LDS dest is wave-uniform base + lane*16B (HW rule); pad sits between chunks.
    #define STAGE(p, tile)                                                        \
        {                                                                         \
            const float* gsrc = zb + (size_t)(tile) * 16 * D_ + w * 256 + l * 4;  \
            float* ldst = &zt[(p)][w * 256];                                      \
            _Pragma("unroll")                                                     \
            for (int r = 0; r < 16; r++) {                                        \
                __builtin_amdgcn_global_load_lds(                                 \
                    (const __attribute__((address_space(1))) unsigned int*)       \
                        (gsrc + (size_t)r * D_),                                  \
                    (__attribute__((address_space(3))) unsigned int*)             \
                        (ldst + r * RPAD),                                        \
                    16, 0, 0);                                                    \
            }                                                                     \
        }

    STAGE(0, 0)
    __syncthreads();   // tile 0 resident

    for (int it = 0; it < NT; it++) {
        int p = it & 1;
        if (it + 1 < NT) STAGE(p ^ 1, it + 1)   // overlaps this tile's compute

        // --- scores: full d per wave, 4 independent MFMA accumulators ---
        f32x4 a0 = {0.f,0.f,0.f,0.f}, a1 = {0.f,0.f,0.f,0.f};
        f32x4 a2 = {0.f,0.f,0.f,0.f}, a3 = {0.f,0.f,0.f,0.f};
        const float* brow = &zt[p][frow * RPAD + fquad * 8];
        #pragma unroll
        for (int i = 0; i < 32; i += 4) {
            float4 z00 = *(const float4*)(brow + (i + 0) * 32);
            float4 z01 = *(const float4*)(brow + (i + 0) * 32 + 4);
            float4 z10 = *(const float4*)(brow + (i + 1) * 32);
            float4 z11 = *(const float4*)(brow + (i + 1) * 32 + 4);
            float4 z20 = *(const float4*)(brow + (i + 2) * 32);
            float4 z21 = *(const float4*)(brow + (i + 2) * 32 + 4);
            float4 z30 = *(const float4*)(brow + (i + 3) * 32);
            float4 z31 = *(const float4*)(brow + (i + 3) * 32 + 4);
            a0 = __builtin_amdgcn_mfma_f32_16x16x32_bf16(rA[i + 0], cvt8(z00, z01), a0, 0, 0, 0);
            a1 = __builtin_amdgcn_mfma_f32_16x16x32_bf16(rA[i + 1], cvt8(z10, z11), a1, 0, 0, 0);
            a2 = __builtin_amdgcn_mfma_f32_16x16x32_bf16(rA[i + 2], cvt8(z20, z21), a2, 0, 0, 0);
            a3 = __builtin_amdgcn_mfma_f32_16x16x32_bf16(rA[i + 3], cvt8(z30, z31), a3, 0, 0, 0);
        }
        f32x4 acc = a0 + a1 + a2 + a3;   // C[h=fquad*4+r][n=frow]

        // --- e = masked exp(s); scores O(0.1) so no max-subtraction ---
        {
            int gn = n0 + it * 16 + frow;
            bool valid = (mask[b * N_ + gn] != 0) || (gn == 0 && anyb == 0);
            float e0 = valid ? __expf(acc[0]) : 0.f;
            float e1 = valid ? __expf(acc[1]) : 0.f;
            float e2 = valid ? __expf(acc[2]) : 0.f;
            float e3 = valid ? __expf(acc[3]) : 0.f;
            l4[0] += e0; l4[1] += e1; l4[2] += e2; l4[3] += e3;
            // Ew[w][n][h] — wave-private, no cross-wave barrier needed
            *(float4*)&Ew[w][frow][fquad * 4] = make_float4(e0, e1, e2, e3);
        }

        // --- ctx: wave w owns d in [256w,+256); lane covers d = 256w+4l..+4 ---
        {
            const float* zcol = &zt[p][w * 256 + 4 * l];
            #pragma unroll 4
            for (int r = 0; r < 16; r++) {
                float4 zr = *(const float4*)(zcol + r * RPAD);
                const float4* er4 = (const float4*)&Ew[w][r][0];
                float4 e0 = er4[0], e1 = er4[1], e2 = er4[2], e3 = er4[3];
                ctx[0].x  += e0.x * zr.x; ctx[0].y  += e0.x * zr.y; ctx[0].z  += e0.x * zr.z; ctx[0].w  += e0.x * zr.w;
                ctx[1].x  += e0.y * zr.x; ctx[1].y  += e0.y * zr.y; ctx[1].z  += e0.y * zr.z; ctx[1].w  += e0.y * zr.w;
                ctx[2].x  += e0.z * zr.x; ctx[2].y  += e0.z * zr.y; ctx[2].z  += e0.z * zr.z; ctx[2].w  += e0.z * zr.w;
                ctx[3].x  += e0.w * zr.x; ctx[3].y  += e0.w * zr.y; ctx[3].z  += e0.w * zr.z; ctx[3].w  += e0.w * zr.w;
                ctx[4].x  += e1.x * zr.x; ctx[4].y  += e1.x * zr.y; ctx[4].z  += e1.x * zr.z; ctx[4].w  += e1.x * zr.w;
                ctx[5].x  += e1.y * zr.x; ctx[5].y  += e1.y * zr.y; ctx[5].z  += e1.y * zr.z; ctx[5].w  += e1.y * zr.w;
                ctx[6].x  += e1.z * zr.x; ctx[6].y  += e1.z * zr.y; ctx[6].z  += e1.z * zr.z; ctx[6].w  += e1.z * zr.w;
                ctx[7].x  += e1.w * zr.x; ctx[7].y  += e1.w * zr.y; ctx[7].z  += e1.w * zr.z; ctx[7].w  += e1.w * zr.w;
                ctx[8].x  += e2.x * zr.x; ctx[8].y  += e2.x * zr.y; ctx[8].z  += e2.x * zr.z; ctx[8].w  += e2.x * zr.w;
                ctx[9].x  += e2.y * zr.x; ctx[9].y  += e2.y * zr.y; ctx[9].z  += e2.y * zr.z; ctx[9].w  += e2.y * zr.w;
                ctx[10].x += e2.z * zr.x; ctx[10].y += e2.z * zr.y; ctx[10].z += e2.z * zr.z; ctx[10].w += e2.z * zr.w;
                ctx[11].x += e2.w * zr.x; ctx[11].y += e2.w * zr.y; ctx[11].z += e2.w * zr.z; ctx[11].w += e2.w * zr.w;
                ctx[12].x += e3.x * zr.x; ctx[12].y += e3.x * zr.y; ctx[12].z += e3.x * zr.z; ctx[12].w += e3.x * zr.w;
                ctx[13].x += e3.y * zr.x; ctx[13].y += e3.y * zr.y; ctx[13].z += e3.y * zr.z; ctx[13].w += e3.y * zr.w;
                ctx[14].x += e3.z * zr.x; ctx[14].y += e3.z * zr.y; ctx[14].z += e3.z * zr.z; ctx[14].w += e3.z * zr.w;
                ctx[15].x += e3.w * zr.x; ctx[15].y += e3.w * zr.y; ctx[15].z += e3.w * zr.z; ctx[15].w += e3.w * zr.w;
            }
        }
        __syncthreads();   // single per-tile barrier: drains prefetch (= the wait we want)
    }

    // --- epilogue: f32 partials + l ---
    {
        float* pp = part + (size_t)bx * 16 * 1024 + w * 256 + 4 * l;
        #pragma unroll
        for (int h = 0; h < 16; h++)
            *(float4*)(pp + h * 1024) = ctx[h];
    }
    if (w == 0) {
        #pragma unroll
        for (int r = 0; r < 4; r++) {
            float v = l4[r];
            v += __shfl_xor(v, 1, 64);
            v += __shfl_xor(v, 2, 64);
            v += __shfl_xor(v, 4, 64);
            v += __shfl_xor(v, 8, 64);
            if (frow == 0) l_part[bx * 16 + fquad * 4 + r] = v;
        }
    }
}

// ---------------------------------------------------------------------------
// gemv_wv_k: block (b,h). Phase A: vlds = (sum_c part[b][c][h][:]) / L[b][h].
// Phase B: pooled[b][64h+j] = w_v[64h+j,:].vlds + b_v (4-acc ILP GEMV).
// ---------------------------------------------------------------------------
__global__ __launch_bounds__(256) void gemv_wv_k(const float* __restrict__ part,
        const float* __restrict__ l_part, const float* __restrict__ w_v,
        const float* __restrict__ b_v, float* __restrict__ pooled) {
    __shared__ __align__(16) float vlds[1024];
    int bx = blockIdx.x, t = threadIdx.x;
    int b = bx >> 4, h = bx & 15;
    float L = 0.f;
    #pragma unroll
    for (int cc = 0; cc < 8; cc++) L += l_part[(b * 8 + cc) * 16 + h];
    float rL = 1.f / L;
    float sx = 0.f, sy = 0.f, sz = 0.f, sw = 0.f;
    #pragma unroll
    for (int cc = 0; cc < 8; cc++) {
        const float4* p4 = (const float4*)&part[(((size_t)(b * 8 + cc)) * 16 + h) * 1024];
        float4 v = p4[t];
        sx += v.x; sy += v.y; sz += v.z; sw += v.w;
    }
    *(float4*)&vlds[4 * t] = make_float4(sx * rL, sy * rL, sz * rL, sw * rL);
    __syncthreads();
    int w = t >> 6, l = t & 63;
    const float4* v4 = (const float4*)vlds;
    float* orow = pooled + (size_t)b * 1024;
    #pragma unroll
    for (int s0 = 0; s0 < 16; s0 += 4) {
        int jb = h * 64 + w * 16 + s0;
        float a0 = 0.f, a1 = 0.f, a2 = 0.f, a3 = 0.f;
        #pragma unroll
        for (int kk = 0; kk < 4; kk++) {
            float4 v = v4[kk * 64 + l];
            float4 w0 = *(const float4*)&w_v[(size_t)(jb + 0) * 1024 + (kk * 64 + l) * 4];
            float4 w1 = *(const float4*)&w_v[(size_t)(jb + 1) * 1024 + (kk * 64 + l) * 4];
            float4 w2 = *(const float4*)&w_v[(size_t)(jb + 2) * 1024 + (kk * 64 + l) * 4];
            float4 w3 = *(const float4*)&w_v[(size_t)(jb + 3) * 1024 + (kk * 64 + l) * 4];
            a0 += w0.x * v.x + w0.y * v.y + w0.z * v.z + w0.w * v.w;
            a1 += w1.x * v.x + w1.y * v.y + w1.z * v.z + w1.w * v.w;
            a2 += w2.x * v.x + w2.y * v.y + w2.z * v.z + w2.w * v.w;
            a3 += w3.x * v.x + w3.y * v.y + w3.z * v.z + w3.w * v.w;
        }
        #pragma unroll
        for (int m = 32; m >= 1; m >>= 1) {
            a0 += __shfl_xor(a0, m, 64); a1 += __shfl_xor(a1, m, 64);
            a2 += __shfl_xor(a2, m, 64); a3 += __shfl_xor(a3, m, 64);
        }
        if (l == 0) {
            orow[jb + 0] = a0 + b_v[jb + 0];
            orow[jb + 1] = a1 + b_v[jb + 1];
            orow[jb + 2] = a2 + b_v[jb + 2];
            orow[jb + 3] = a3 + b_v[jb + 3];
        }
    }
}

// ---------------------------------------------------------------------------
// gemv_wo_k: block (b,q). out[b][64q+j] = w_o[64q+j,:].pooled[b] + b_o
// ---------------------------------------------------------------------------
__global__ __launch_bounds__(256) void gemv_wo_k(const float* __restrict__ pooled,
        const float* __restrict__ w_o, const float* __restrict__ b_o,
        float* __restrict__ out) {
    __shared__ __align__(16) float vlds[1024];
    int bx = blockIdx.x, t = threadIdx.x;
    int b = bx >> 4, q = bx & 15;
    *(float4*)&vlds[4 * t] = *(const float4*)&pooled[(size_t)b * 1024 + 4 * t];
    __syncthreads();
    int w = t >> 6, l = t & 63;
    const float4* v4 = (const float4*)vlds;
    float* orow = out + (size_t)b * 1024;
    #pragma unroll
    for (int s0 = 0; s0 < 16; s0 += 4) {
        int jb = q * 64 + w * 16 + s0;
        float a0 = 0.f, a1 = 0.f, a2 = 0.f, a3 = 0.f;
        #pragma unroll
        for (int kk = 0; kk < 4; kk++) {
            float4 v = v4[kk * 64 + l];
            float4 w0 = *(const float4*)&w_o[(size_t)(jb + 0) * 1024 + (kk * 64 + l) * 4];
            float4 w1 = *(const float4*)&w_o[(size_t)(jb + 1) * 1024 + (kk * 64 + l) * 4];
            float4 w2 = *(const float4*)&w_o[(size_t)(jb + 2) * 1024 + (kk * 64 + l) * 4];
            float4 w3 = *(const float4*)&w_o[(size_t)(jb + 3) * 1024 + (kk * 64 + l) * 4];
            a0 += w0.x * v.x + w0.y * v.y + w0.z * v.z + w0.w * v.w;
            a1 += w1.x * v.x + w1.y * v.y + w1.z * v.z + w1.w * v.w;
            a2 += w2.x * v.x + w2.y * v.y + w2.z * v.z + w2.w * v.w;
            a3 += w3.x * v.x + w3.y * v.y + w3.z * v.z + w3.w * v.w;
        }
        #pragma unroll
        for (int m = 32; m >= 1; m >>= 1) {
            a0 += __shfl_xor(a0, m, 64); a1 += __shfl_xor(a1, m, 64);
            a2 += __shfl_xor(a2, m, 64); a3 += __shfl_xor(a3, m, 64);
        }
        if (l == 0) {
            orow[jb + 0] = a0 + b_o[jb + 0];
            orow[jb + 1] = a1 + b_o[jb + 1];
            orow[jb + 2] = a2 + b_o[jb + 2];
            orow[jb + 3] = a3 + b_o[jb + 3];
        }
    }
}

// ---------------------------------------------------------------------------
extern "C" void kernel_launch(void* const* d_in, const int* in_sizes, int n_in,
                              void* d_out, int out_size, void* d_ws, size_t ws_size,
                              hipStream_t stream) {
    const float* z     = (const float*)d_in[0];
    const int*   mask  = (const int*)d_in[1];
    const float* query = (const float*)d_in[2];
    const float* w_q   = (const float*)d_in[3];
    const float* w_k   = (const float*)d_in[4];
    const float* w_v   = (const float*)d_in[5];
    const float* b_q   = (const float*)d_in[6];
    // d_in[7] = b_k: constant per (b,h) over n -> cancels in softmax
    const float* b_v   = (const float*)d_in[8];
    const float* w_o   = (const float*)d_in[9];
    const float* b_o   = (const float*)d_in[10];
    float* out = (float*)d_out;

    char* ws = (char*)d_ws;
    unsigned short* rAf    = (unsigned short*)(ws + 0);       // 32 KB
    float*          q_ws   = (float*)(ws + 32768);            // 4 KB
    int*            any_ws = (int*)(ws + 36864);              // 128 B
    float*          l_part = (float*)(ws + 40960);            // 16 KB
    float*          pooled = (float*)(ws + 65536);            // 128 KB
    float*          part   = (float*)(ws + 1048576);          // 16 MB

    prep_q<<<96, 256, 0, stream>>>(query, w_q, b_q, mask, q_ws, any_ws);
    prep_r<<<64, 256, 0, stream>>>(q_ws, w_k, rAf);
    main_k<<<256, 256, 0, stream>>>(z, mask, any_ws, rAf, part, l_part);
    gemv_wv_k<<<512, 256, 0, stream>>>(part, l_part, w_v, b_v, pooled);
    gemv_wo_k<<<512, 256, 0, stream>>>(pooled, w_o, b_o, out);
}

// Round 4
// 457.363 us; speedup vs baseline: 1.6032x; 1.0062x over previous
//
#include <hip/hip_runtime.h>
#include <hip/hip_bf16.h>
#include <stdint.h>

#define B_ 32
#define N_ 2048
#define D_ 1024
#define H_ 16

#define NT 16          // 16-row tiles per block (256 rows/block)
#define RPAD 1028      // f32 row stride in LDS (+4 pad: 2-way-max bank aliasing)

typedef __attribute__((ext_vector_type(8))) short short8;
typedef __attribute__((ext_vector_type(4))) float f32x4;

__device__ __forceinline__ unsigned short f2bf(float x) {
    unsigned u = __float_as_uint(x);
    u += 0x7FFFu + ((u >> 16) & 1u);   // RNE
    return (unsigned short)(u >> 16);
}
__device__ __forceinline__ float bflo(unsigned u) { return __uint_as_float(u << 16); }

// pack 8 f32 -> short8 bf16 (RNE packed cvt)
__device__ __forceinline__ short8 cvt8(float4 a, float4 b) {
    union { __hip_bfloat162 h[4]; short8 s; } u;
    u.h[0] = __float22bfloat162_rn(make_float2(a.x, a.y));
    u.h[1] = __float22bfloat162_rn(make_float2(a.z, a.w));
    u.h[2] = __float22bfloat162_rn(make_float2(b.x, b.y));
    u.h[3] = __float22bfloat162_rn(make_float2(b.z, b.w));
    return u.s;
}

// ---------------------------------------------------------------------------
// prep_k (fused): blocks 0..63 (h=bx>>2, dg=bx&3):
//   phase 1: q_h[j] = query . w_q[64h+j,:] + b_q[64h+j]      (j in [0,64))
//   phase 2: R[h][d] = 0.125 * sum_j q_h[j] w_k[64h+j][d], d in [256dg,+256),
//            packed directly as bf16 MFMA A-fragments.
// blocks 64..95: any_ws[b] = OR over mask row (b = bx-64).
// ---------------------------------------------------------------------------
__global__ __launch_bounds__(256) void prep_k(const float* __restrict__ query,
        const float* __restrict__ w_q, const float* __restrict__ b_q,
        const float* __restrict__ w_k, const int* __restrict__ mask,
        unsigned short* __restrict__ rAf, int* __restrict__ any_ws) {
    __shared__ __align__(16) float qv[1024];
    __shared__ float qp[64][5];
    __shared__ float qh[64];
    __shared__ int wf[4];
    int bx = blockIdx.x, t = threadIdx.x;
    if (bx < 64) {
        int h = bx >> 2, dg = bx & 3;
        *(float4*)&qv[4 * t] = *(const float4*)&query[4 * t];
        __syncthreads();
        // ---- phase 1: q row (64 outputs, 4 threads per output) ----
        {
            int j = t >> 2, sub = t & 3;
            const float4* wq4 = (const float4*)(w_q + (size_t)(h * 64 + j) * 1024);
            const float4* qv4 = (const float4*)qv;
            float a = 0.f;
            #pragma unroll 8
            for (int kk = 0; kk < 64; kk++) {
                float4 wv = wq4[sub * 64 + kk];
                float4 vv = qv4[sub * 64 + kk];
                a += wv.x * vv.x + wv.y * vv.y + wv.z * vv.z + wv.w * vv.w;
            }
            qp[j][sub] = a;
        }
        __syncthreads();
        if (t < 64)
            qh[t] = qp[t][0] + qp[t][1] + qp[t][2] + qp[t][3] + b_q[h * 64 + t];
        __syncthreads();
        // ---- phase 2: R slice, pack A-fragment ----
        int d = dg * 256 + t;
        float acc = 0.f;
        #pragma unroll 8
        for (int j = 0; j < 64; j++)
            acc += qh[j] * w_k[(size_t)(h * 64 + j) * 1024 + d];
        acc *= 0.125f;                       // 1/sqrt(64) folded into R
        int i = d >> 5, fq = (d >> 3) & 3, jj = d & 7;
        int lane = (fq << 4) | h;            // A[m=lane&15][k=(lane>>4)*8+j]
        rAf[(size_t)(i * 64 + lane) * 8 + jj] = f2bf(acc);
    } else {
        int b = bx - 64;
        int v = 0;
        for (int k = 0; k < 8; k++) v |= mask[b * N_ + k * 256 + t];
        unsigned long long bal = __ballot(v != 0);
        int w = t >> 6;
        if ((t & 63) == 0) wf[w] = (bal != 0ull) ? 1 : 0;
        __syncthreads();
        if (t == 0) any_ws[b] = wf[0] | wf[1] | wf[2] | wf[3];
    }
}

// ---------------------------------------------------------------------------
// main_k: grid 256 (b=bx>>3, chunk c=bx&7 -> 256 rows, 16 x 16-row tiles).
// f32 z tile staged via global_load_lds (async, zero VGPR), double-buffered;
// ONE __syncthreads per tile — its vmcnt(0) drain IS the prefetch wait.
// Every wave computes full-d scores (32 MFMA, A-frags in 128 VGPRs) so no
// cross-wave reduction barrier; E tile is wave-private LDS.
// Partials written as bf16 (halves epilogue traffic; error ~1e-4, verified r1).
// ---------------------------------------------------------------------------
__global__ __launch_bounds__(256, 1) void main_k(const float* __restrict__ z,
        const int* __restrict__ mask, const int* __restrict__ any_ws,
        const unsigned short* __restrict__ rAf,
        unsigned short* __restrict__ part, float* __restrict__ l_part) {
    __shared__ __align__(16) float zt[2][16 * RPAD];   // 131,584 B
    __shared__ __align__(16) float Ew[4][16][16];      // wave-private e[n][h]
    int bx = blockIdx.x, t = threadIdx.x;
    int b = bx >> 3, c = bx & 7;
    int n0 = c * 256;
    int w = t >> 6, l = t & 63;
    int frow = l & 15, fquad = l >> 4;
    int anyb = any_ws[b];

    // preload all 32 A-fragments (128 VGPRs, launch_bounds(256,1) -> no spill)
    short8 rA[32];
    {
        const short8* rA8 = (const short8*)rAf;
        #pragma unroll
        for (int i = 0; i < 32; i++) rA[i] = rA8[i * 64 + l];
    }
    const float* zb = z + (size_t)b * N_ * D_ + n0 * D_;

    float4 ctx[16];
    #pragma unroll
    for (int h = 0; h < 16; h++) ctx[h] = make_float4(0.f, 0.f, 0.f, 0.f);
    float l4[4] = {0.f, 0.f, 0.f, 0.f};

    // async stage one 16-row tile: wave w loads quarter w of each row.
    // LDS dest is wave-uniform base + lane*16B (HW rule); pad sits between chunks.
    #define STAGE(p, tile)                                                        \
        {                                                                         \
            const float* gsrc = zb + (size_t)(tile) * 16 * D_ + w * 256 + l * 4;  \
            float* ldst = &zt[(p)][w * 256];                                      \
            _Pragma("unroll")                                                     \
            for (int r = 0; r < 16; r++) {                                        \
                __builtin_amdgcn_global_load_lds(                                 \
                    (const __attribute__((address_space(1))) unsigned int*)       \
                        (gsrc + (size_t)r * D_),                                  \
                    (__attribute__((address_space(3))) unsigned int*)             \
                        (ldst + r * RPAD),                                        \
                    16, 0, 0);                                                    \
            }                                                                     \
        }

    STAGE(0, 0)
    __syncthreads();   // tile 0 resident

    for (int it = 0; it < NT; it++) {
        int p = it & 1;
        if (it + 1 < NT) STAGE(p ^ 1, it + 1)   // overlaps this tile's compute

        // --- scores: full d per wave, 4 independent MFMA accumulators ---
        f32x4 a0 = {0.f,0.f,0.f,0.f}, a1 = {0.f,0.f,0.f,0.f};
        f32x4 a2 = {0.f,0.f,0.f,0.f}, a3 = {0.f,0.f,0.f,0.f};
        const float* brow = &zt[p][frow * RPAD + fquad * 8];
        #pragma unroll
        for (int i = 0; i < 32; i += 4) {
            float4 z00 = *(const float4*)(brow + (i + 0) * 32);
            float4 z01 = *(const float4*)(brow + (i + 0) * 32 + 4);
            float4 z10 = *(const float4*)(brow + (i + 1) * 32);
            float4 z11 = *(const float4*)(brow + (i + 1) * 32 + 4);
            float4 z20 = *(const float4*)(brow + (i + 2) * 32);
            float4 z21 = *(const float4*)(brow + (i + 2) * 32 + 4);
            float4 z30 = *(const float4*)(brow + (i + 3) * 32);
            float4 z31 = *(const float4*)(brow + (i + 3) * 32 + 4);
            a0 = __builtin_amdgcn_mfma_f32_16x16x32_bf16(rA[i + 0], cvt8(z00, z01), a0, 0, 0, 0);
            a1 = __builtin_amdgcn_mfma_f32_16x16x32_bf16(rA[i + 1], cvt8(z10, z11), a1, 0, 0, 0);
            a2 = __builtin_amdgcn_mfma_f32_16x16x32_bf16(rA[i + 2], cvt8(z20, z21), a2, 0, 0, 0);
            a3 = __builtin_amdgcn_mfma_f32_16x16x32_bf16(rA[i + 3], cvt8(z30, z31), a3, 0, 0, 0);
        }
        f32x4 acc = a0 + a1 + a2 + a3;   // C[h=fquad*4+r][n=frow]

        // --- e = masked exp(s); scores O(0.1) so no max-subtraction ---
        {
            int gn = n0 + it * 16 + frow;
            bool valid = (mask[b * N_ + gn] != 0) || (gn == 0 && anyb == 0);
            float e0 = valid ? __expf(acc[0]) : 0.f;
            float e1 = valid ? __expf(acc[1]) : 0.f;
            float e2 = valid ? __expf(acc[2]) : 0.f;
            float e3 = valid ? __expf(acc[3]) : 0.f;
            l4[0] += e0; l4[1] += e1; l4[2] += e2; l4[3] += e3;
            // Ew[w][n][h] — wave-private, no cross-wave barrier needed
            *(float4*)&Ew[w][frow][fquad * 4] = make_float4(e0, e1, e2, e3);
        }

        // --- ctx: wave w owns d in [256w,+256); lane covers d = 256w+4l..+4 ---
        {
            const float* zcol = &zt[p][w * 256 + 4 * l];
            #pragma unroll 4
            for (int r = 0; r < 16; r++) {
                float4 zr = *(const float4*)(zcol + r * RPAD);
                const float4* er4 = (const float4*)&Ew[w][r][0];
                float4 e0 = er4[0], e1 = er4[1], e2 = er4[2], e3 = er4[3];
                ctx[0].x  += e0.x * zr.x; ctx[0].y  += e0.x * zr.y; ctx[0].z  += e0.x * zr.z; ctx[0].w  += e0.x * zr.w;
                ctx[1].x  += e0.y * zr.x; ctx[1].y  += e0.y * zr.y; ctx[1].z  += e0.y * zr.z; ctx[1].w  += e0.y * zr.w;
                ctx[2].x  += e0.z * zr.x; ctx[2].y  += e0.z * zr.y; ctx[2].z  += e0.z * zr.z; ctx[2].w  += e0.z * zr.w;
                ctx[3].x  += e0.w * zr.x; ctx[3].y  += e0.w * zr.y; ctx[3].z  += e0.w * zr.z; ctx[3].w  += e0.w * zr.w;
                ctx[4].x  += e1.x * zr.x; ctx[4].y  += e1.x * zr.y; ctx[4].z  += e1.x * zr.z; ctx[4].w  += e1.x * zr.w;
                ctx[5].x  += e1.y * zr.x; ctx[5].y  += e1.y * zr.y; ctx[5].z  += e1.y * zr.z; ctx[5].w  += e1.y * zr.w;
                ctx[6].x  += e1.z * zr.x; ctx[6].y  += e1.z * zr.y; ctx[6].z  += e1.z * zr.z; ctx[6].w  += e1.z * zr.w;
                ctx[7].x  += e1.w * zr.x; ctx[7].y  += e1.w * zr.y; ctx[7].z  += e1.w * zr.z; ctx[7].w  += e1.w * zr.w;
                ctx[8].x  += e2.x * zr.x; ctx[8].y  += e2.x * zr.y; ctx[8].z  += e2.x * zr.z; ctx[8].w  += e2.x * zr.w;
                ctx[9].x  += e2.y * zr.x; ctx[9].y  += e2.y * zr.y; ctx[9].z  += e2.y * zr.z; ctx[9].w  += e2.y * zr.w;
                ctx[10].x += e2.z * zr.x; ctx[10].y += e2.z * zr.y; ctx[10].z += e2.z * zr.z; ctx[10].w += e2.z * zr.w;
                ctx[11].x += e2.w * zr.x; ctx[11].y += e2.w * zr.y; ctx[11].z += e2.w * zr.z; ctx[11].w += e2.w * zr.w;
                ctx[12].x += e3.x * zr.x; ctx[12].y += e3.x * zr.y; ctx[12].z += e3.x * zr.z; ctx[12].w += e3.x * zr.w;
                ctx[13].x += e3.y * zr.x; ctx[13].y += e3.y * zr.y; ctx[13].z += e3.y * zr.z; ctx[13].w += e3.y * zr.w;
                ctx[14].x += e3.z * zr.x; ctx[14].y += e3.z * zr.y; ctx[14].z += e3.z * zr.z; ctx[14].w += e3.z * zr.w;
                ctx[15].x += e3.w * zr.x; ctx[15].y += e3.w * zr.y; ctx[15].z += e3.w * zr.z; ctx[15].w += e3.w * zr.w;
            }
        }
        __syncthreads();   // single per-tile barrier: drains prefetch (= the wait we want)
    }

    // --- epilogue: bf16 partials + f32 l ---
    {
        unsigned short* pp = part + (size_t)bx * 16 * 1024 + w * 256 + 4 * l;
        #pragma unroll
        for (int h = 0; h < 16; h++) {
            ushort4 o;
            o.x = f2bf(ctx[h].x); o.y = f2bf(ctx[h].y);
            o.z = f2bf(ctx[h].z); o.w = f2bf(ctx[h].w);
            *(ushort4*)(pp + h * 1024) = o;
        }
    }
    if (w == 0) {
        #pragma unroll
        for (int r = 0; r < 4; r++) {
            float v = l4[r];
            v += __shfl_xor(v, 1, 64);
            v += __shfl_xor(v, 2, 64);
            v += __shfl_xor(v, 4, 64);
            v += __shfl_xor(v, 8, 64);
            if (frow == 0) l_part[bx * 16 + fquad * 4 + r] = v;
        }
    }
}

// ---------------------------------------------------------------------------
// gemv_wv_k: block (b,h). Phase A: vlds = (sum_c part[b][c][h][:]) / L[b][h].
// Phase B: pooled[b][64h+j] = w_v[64h+j,:].vlds + b_v (4-acc ILP GEMV).
// ---------------------------------------------------------------------------
__global__ __launch_bounds__(256) void gemv_wv_k(const unsigned short* __restrict__ part,
        const float* __restrict__ l_part, const float* __restrict__ w_v,
        const float* __restrict__ b_v, float* __restrict__ pooled) {
    __shared__ __align__(16) float vlds[1024];
    int bx = blockIdx.x, t = threadIdx.x;
    int b = bx >> 4, h = bx & 15;
    float L = 0.f;
    #pragma unroll
    for (int cc = 0; cc < 8; cc++) L += l_part[(b * 8 + cc) * 16 + h];
    float rL = 1.f / L;
    float sx = 0.f, sy = 0.f, sz = 0.f, sw = 0.f;
    #pragma unroll
    for (int cc = 0; cc < 8; cc++) {
        const ushort4* p4 = (const ushort4*)&part[(((size_t)(b * 8 + cc)) * 16 + h) * 1024];
        ushort4 u = p4[t];
        sx += bflo(u.x); sy += bflo(u.y); sz += bflo(u.z); sw += bflo(u.w);
    }
    *(float4*)&vlds[4 * t] = make_float4(sx * rL, sy * rL, sz * rL, sw * rL);
    __syncthreads();
    int w = t >> 6, l = t & 63;
    const float4* v4 = (const float4*)vlds;
    float* orow = pooled + (size_t)b * 1024;
    #pragma unroll
    for (int s0 = 0; s0 < 16; s0 += 4) {
        int jb = h * 64 + w * 16 + s0;
        float a0 = 0.f, a1 = 0.f, a2 = 0.f, a3 = 0.f;
        #pragma unroll
        for (int kk = 0; kk < 4; kk++) {
            float4 v = v4[kk * 64 + l];
            float4 w0 = *(const float4*)&w_v[(size_t)(jb + 0) * 1024 + (kk * 64 + l) * 4];
            float4 w1 = *(const float4*)&w_v[(size_t)(jb + 1) * 1024 + (kk * 64 + l) * 4];
            float4 w2 = *(const float4*)&w_v[(size_t)(jb + 2) * 1024 + (kk * 64 + l) * 4];
            float4 w3 = *(const float4*)&w_v[(size_t)(jb + 3) * 1024 + (kk * 64 + l) * 4];
            a0 += w0.x * v.x + w0.y * v.y + w0.z * v.z + w0.w * v.w;
            a1 += w1.x * v.x + w1.y * v.y + w1.z * v.z + w1.w * v.w;
            a2 += w2.x * v.x + w2.y * v.y + w2.z * v.z + w2.w * v.w;
            a3 += w3.x * v.x + w3.y * v.y + w3.z * v.z + w3.w * v.w;
        }
        #pragma unroll
        for (int m = 32; m >= 1; m >>= 1) {
            a0 += __shfl_xor(a0, m, 64); a1 += __shfl_xor(a1, m, 64);
            a2 += __shfl_xor(a2, m, 64); a3 += __shfl_xor(a3, m, 64);
        }
        if (l == 0) {
            orow[jb + 0] = a0 + b_v[jb + 0];
            orow[jb + 1] = a1 + b_v[jb + 1];
            orow[jb + 2] = a2 + b_v[jb + 2];
            orow[jb + 3] = a3 + b_v[jb + 3];
        }
    }
}

// ---------------------------------------------------------------------------
// gemv_wo_k: block (b,q). out[b][64q+j] = w_o[64q+j,:].pooled[b] + b_o
// ---------------------------------------------------------------------------
__global__ __launch_bounds__(256) void gemv_wo_k(const float* __restrict__ pooled,
        const float* __restrict__ w_o, const float* __restrict__ b_o,
        float* __restrict__ out) {
    __shared__ __align__(16) float vlds[1024];
    int bx = blockIdx.x, t = threadIdx.x;
    int b = bx >> 4, q = bx & 15;
    *(float4*)&vlds[4 * t] = *(const float4*)&pooled[(size_t)b * 1024 + 4 * t];
    __syncthreads();
    int w = t >> 6, l = t & 63;
    const float4* v4 = (const float4*)vlds;
    float* orow = out + (size_t)b * 1024;
    #pragma unroll
    for (int s0 = 0; s0 < 16; s0 += 4) {
        int jb = q * 64 + w * 16 + s0;
        float a0 = 0.f, a1 = 0.f, a2 = 0.f, a3 = 0.f;
        #pragma unroll
        for (int kk = 0; kk < 4; kk++) {
            float4 v = v4[kk * 64 + l];
            float4 w0 = *(const float4*)&w_o[(size_t)(jb + 0) * 1024 + (kk * 64 + l) * 4];
            float4 w1 = *(const float4*)&w_o[(size_t)(jb + 1) * 1024 + (kk * 64 + l) * 4];
            float4 w2 = *(const float4*)&w_o[(size_t)(jb + 2) * 1024 + (kk * 64 + l) * 4];
            float4 w3 = *(const float4*)&w_o[(size_t)(jb + 3) * 1024 + (kk * 64 + l) * 4];
            a0 += w0.x * v.x + w0.y * v.y + w0.z * v.z + w0.w * v.w;
            a1 += w1.x * v.x + w1.y * v.y + w1.z * v.z + w1.w * v.w;
            a2 += w2.x * v.x + w2.y * v.y + w2.z * v.z + w2.w * v.w;
            a3 += w3.x * v.x + w3.y * v.y + w3.z * v.z + w3.w * v.w;
        }
        #pragma unroll
        for (int m = 32; m >= 1; m >>= 1) {
            a0 += __shfl_xor(a0, m, 64); a1 += __shfl_xor(a1, m, 64);
            a2 += __shfl_xor(a2, m, 64); a3 += __shfl_xor(a3, m, 64);
        }
        if (l == 0) {
            orow[jb + 0] = a0 + b_o[jb + 0];
            orow[jb + 1] = a1 + b_o[jb + 1];
            orow[jb + 2] = a2 + b_o[jb + 2];
            orow[jb + 3] = a3 + b_o[jb + 3];
        }
    }
}

// ---------------------------------------------------------------------------
extern "C" void kernel_launch(void* const* d_in, const int* in_sizes, int n_in,
                              void* d_out, int out_size, void* d_ws, size_t ws_size,
                              hipStream_t stream) {
    const float* z     = (const float*)d_in[0];
    const int*   mask  = (const int*)d_in[1];
    const float* query = (const float*)d_in[2];
    const float* w_q   = (const float*)d_in[3];
    const float* w_k   = (const float*)d_in[4];
    const float* w_v   = (const float*)d_in[5];
    const float* b_q   = (const float*)d_in[6];
    // d_in[7] = b_k: constant per (b,h) over n -> cancels in softmax
    const float* b_v   = (const float*)d_in[8];
    const float* w_o   = (const float*)d_in[9];
    const float* b_o   = (const float*)d_in[10];
    float* out = (float*)d_out;

    char* ws = (char*)d_ws;
    unsigned short* rAf    = (unsigned short*)(ws + 0);       // 32 KB
    int*            any_ws = (int*)(ws + 32768);              // 128 B
    float*          l_part = (float*)(ws + 40960);            // 16 KB
    float*          pooled = (float*)(ws + 65536);            // 128 KB
    unsigned short* part   = (unsigned short*)(ws + 1048576); // 8 MB

    prep_k<<<96, 256, 0, stream>>>(query, w_q, b_q, w_k, mask, rAf, any_ws);
    main_k<<<256, 256, 0, stream>>>(z, mask, any_ws, rAf, part, l_part);
    gemv_wv_k<<<512, 256, 0, stream>>>(part, l_part, w_v, b_v, pooled);
    gemv_wo_k<<<512, 256, 0, stream>>>(pooled, w_o, b_o, out);
}